// Round 6
// baseline (5422.423 us; speedup 1.0000x reference)
//
#include <hip/hip_runtime.h>

#define FLT_MAX_C 3.402823466e+38f

typedef __attribute__((ext_vector_type(8))) __bf16 bf16x8;
typedef __attribute__((ext_vector_type(4))) float f32x4;

static __device__ __forceinline__ ushort f2bf(float x) {
    union { float f; unsigned u; } v; v.f = x;
    unsigned r = (v.u + 0x7FFFu + ((v.u >> 16) & 1u)) >> 16;
    return (ushort)r;
}

// ================= fp32 GEMM device body (BM=128, BN=128, BK=16) ==========
// 256 threads, 8x8 micro-tile in split-halves layout; LDS reads are
// 16B-consecutive per 16-lane group (2-way = free) or broadcast.
template<bool RELU>
__device__ __forceinline__ void gemm_f32_dev(
    const float* __restrict__ A, const float* __restrict__ W,
    const float* __restrict__ bias, float* __restrict__ C, int K, int N)
{
    __shared__ float As[16][128];
    __shared__ float Bs[16][132];
    const int tid = threadIdx.x;
    const int bm = blockIdx.y << 7;
    const int bn = blockIdx.x << 7;

    const int la_row = tid >> 1;          // 0..127
    const int la_k   = (tid & 1) << 2;    // 0 or 4 (plus +8 pass)
    const int lb_row = tid >> 5;          // 0..7  (plus +8 pass)
    const int lb_col = (tid & 31) << 2;   // 0..124
    const int tm4 = (tid >> 4) << 2;      // 0..60
    const int tn4 = (tid & 15) << 2;      // 0..60

    float acc[8][8];
    #pragma unroll
    for (int i = 0; i < 8; ++i)
        #pragma unroll
        for (int j = 0; j < 8; ++j) acc[i][j] = 0.f;

    const float* aptr = A + (size_t)(bm + la_row) * K + la_k;
    const float* bptr = W + (size_t)lb_row * N + bn + lb_col;

    float4 av0 = *(const float4*)(aptr);
    float4 av1 = *(const float4*)(aptr + 8);
    float4 bv0 = *(const float4*)(bptr);
    float4 bv1 = *(const float4*)(bptr + (size_t)8 * N);

    for (int k0 = 0; k0 < K; k0 += 16) {
        __syncthreads();
        As[la_k + 0][la_row] = av0.x;
        As[la_k + 1][la_row] = av0.y;
        As[la_k + 2][la_row] = av0.z;
        As[la_k + 3][la_row] = av0.w;
        As[la_k + 8][la_row] = av1.x;
        As[la_k + 9][la_row] = av1.y;
        As[la_k + 10][la_row] = av1.z;
        As[la_k + 11][la_row] = av1.w;
        *(float4*)(&Bs[lb_row][lb_col]) = bv0;
        *(float4*)(&Bs[lb_row + 8][lb_col]) = bv1;
        __syncthreads();
        if (k0 + 16 < K) {   // prefetch next slab under the compute
            av0 = *(const float4*)(aptr + k0 + 16);
            av1 = *(const float4*)(aptr + k0 + 24);
            bv0 = *(const float4*)(bptr + (size_t)(k0 + 16) * N);
            bv1 = *(const float4*)(bptr + (size_t)(k0 + 24) * N);
        }
        #pragma unroll
        for (int kk = 0; kk < 16; ++kk) {
            float a[8], b[8];
            *(float4*)(a)     = *(const float4*)(&As[kk][tm4]);
            *(float4*)(a + 4) = *(const float4*)(&As[kk][tm4 + 64]);
            *(float4*)(b)     = *(const float4*)(&Bs[kk][tn4]);
            *(float4*)(b + 4) = *(const float4*)(&Bs[kk][tn4 + 64]);
            #pragma unroll
            for (int i = 0; i < 8; ++i)
                #pragma unroll
                for (int j = 0; j < 8; ++j)
                    acc[i][j] = fmaf(a[i], b[j], acc[i][j]);
        }
    }

    float bv[8];
    #pragma unroll
    for (int j = 0; j < 8; ++j)
        bv[j] = bias[bn + tn4 + (j < 4 ? j : 60 + j)];

    #pragma unroll
    for (int i = 0; i < 8; ++i) {
        int row = bm + tm4 + (i < 4 ? i : 60 + i);
        float* cp = C + (size_t)row * N + bn + tn4;
        float4 v0, v1;
        v0.x = acc[i][0] + bv[0]; v0.y = acc[i][1] + bv[1];
        v0.z = acc[i][2] + bv[2]; v0.w = acc[i][3] + bv[3];
        v1.x = acc[i][4] + bv[4]; v1.y = acc[i][5] + bv[5];
        v1.z = acc[i][6] + bv[6]; v1.w = acc[i][7] + bv[7];
        if (RELU) {
            v0.x = fmaxf(v0.x, 0.f); v0.y = fmaxf(v0.y, 0.f);
            v0.z = fmaxf(v0.z, 0.f); v0.w = fmaxf(v0.w, 0.f);
            v1.x = fmaxf(v1.x, 0.f); v1.y = fmaxf(v1.y, 0.f);
            v1.z = fmaxf(v1.z, 0.f); v1.w = fmaxf(v1.w, 0.f);
        }
        *(float4*)(cp) = v0;
        *(float4*)(cp + 64) = v1;
    }
}

// ========== fp32 GEMM small-M body (BM=64, BN=128, BK=16) ==========
// For the K=512 -> N=128 layer: doubles workgroup count (latency-bound fix).
template<bool RELU>
__device__ __forceinline__ void gemm_f32_64_dev(
    const float* __restrict__ A, const float* __restrict__ W,
    const float* __restrict__ bias, float* __restrict__ C, int K, int N)
{
    __shared__ float As[16][64];
    __shared__ float Bs[16][132];
    const int tid = threadIdx.x;
    const int bm = blockIdx.y << 6;
    const int bn = blockIdx.x << 7;

    const int la_row = tid & 63;          // 0..63
    const int la_k   = (tid >> 6) << 2;   // 0,4,8,12
    const int lb_row = tid >> 5;          // 0..7 (plus +8)
    const int lb_col = (tid & 31) << 2;
    const int tr = tid >> 4;              // 0..15 -> rows tr*4..+3
    const int tc = tid & 15;              // cols tc*4 + {0,64}

    float acc[4][8];
    #pragma unroll
    for (int i = 0; i < 4; ++i)
        #pragma unroll
        for (int j = 0; j < 8; ++j) acc[i][j] = 0.f;

    const float* aptr = A + (size_t)(bm + la_row) * K + la_k;
    const float* bptr = W + (size_t)lb_row * N + bn + lb_col;

    float4 av = *(const float4*)(aptr);
    float4 bv0 = *(const float4*)(bptr);
    float4 bv1 = *(const float4*)(bptr + (size_t)8 * N);

    for (int k0 = 0; k0 < K; k0 += 16) {
        __syncthreads();
        As[la_k + 0][la_row] = av.x;
        As[la_k + 1][la_row] = av.y;
        As[la_k + 2][la_row] = av.z;
        As[la_k + 3][la_row] = av.w;
        *(float4*)(&Bs[lb_row][lb_col]) = bv0;
        *(float4*)(&Bs[lb_row + 8][lb_col]) = bv1;
        __syncthreads();
        if (k0 + 16 < K) {
            av  = *(const float4*)(aptr + k0 + 16);
            bv0 = *(const float4*)(bptr + (size_t)(k0 + 16) * N);
            bv1 = *(const float4*)(bptr + (size_t)(k0 + 24) * N);
        }
        #pragma unroll
        for (int kk = 0; kk < 16; ++kk) {
            float a[4], b[8];
            *(float4*)(a) = *(const float4*)(&As[kk][tr << 2]);
            *(float4*)(b)     = *(const float4*)(&Bs[kk][tc << 2]);
            *(float4*)(b + 4) = *(const float4*)(&Bs[kk][(tc << 2) + 64]);
            #pragma unroll
            for (int i = 0; i < 4; ++i)
                #pragma unroll
                for (int j = 0; j < 8; ++j)
                    acc[i][j] = fmaf(a[i], b[j], acc[i][j]);
        }
    }

    float bb[8];
    #pragma unroll
    for (int j = 0; j < 8; ++j)
        bb[j] = bias[bn + (tc << 2) + (j < 4 ? j : 60 + j)];

    #pragma unroll
    for (int i = 0; i < 4; ++i) {
        float* cp = C + (size_t)(bm + (tr << 2) + i) * N + bn + (tc << 2);
        float4 v0, v1;
        v0.x = acc[i][0] + bb[0]; v0.y = acc[i][1] + bb[1];
        v0.z = acc[i][2] + bb[2]; v0.w = acc[i][3] + bb[3];
        v1.x = acc[i][4] + bb[4]; v1.y = acc[i][5] + bb[5];
        v1.z = acc[i][6] + bb[6]; v1.w = acc[i][7] + bb[7];
        if (RELU) {
            v0.x = fmaxf(v0.x, 0.f); v0.y = fmaxf(v0.y, 0.f);
            v0.z = fmaxf(v0.z, 0.f); v0.w = fmaxf(v0.w, 0.f);
            v1.x = fmaxf(v1.x, 0.f); v1.y = fmaxf(v1.y, 0.f);
            v1.z = fmaxf(v1.z, 0.f); v1.w = fmaxf(v1.w, 0.f);
        }
        *(float4*)(cp) = v0;
        *(float4*)(cp + 64) = v1;
    }
}

// ================= bf16 MFMA GEMM device body (decoder) =================
template<bool RELU, bool OUTF32>
__device__ __forceinline__ void gemm_bf16_dev(
    const ushort* __restrict__ A, const ushort* __restrict__ Wt,
    const float* __restrict__ bias, void* __restrict__ C, int K, int N)
{
    __shared__ __align__(16) ushort As[128][64];
    __shared__ __align__(16) ushort Bs[128][64];
    const int tid  = threadIdx.x;
    const int lane = tid & 63;
    const int wv   = tid >> 6;
    const int wm   = (wv >> 1) << 6;
    const int wn   = (wv & 1) << 6;
    const int bm   = blockIdx.y << 7;
    const int bn   = blockIdx.x << 7;
    const int lr   = lane & 15;
    const int lh   = lane >> 4;

    f32x4 acc[4][4];
    #pragma unroll
    for (int m = 0; m < 4; ++m)
        #pragma unroll
        for (int n = 0; n < 4; ++n) acc[m][n] = (f32x4){0.f, 0.f, 0.f, 0.f};

    for (int k0 = 0; k0 < K; k0 += 64) {
        __syncthreads();
        #pragma unroll
        for (int i = 0; i < 4; ++i) {
            const int c    = wv * 4 + i;
            const int boff = c * 1024 + lane * 16;
            const int r    = boff >> 7;
            const int cbt  = boff & 127;
            const char* sa = (const char*)A  + (((size_t)(bm + r) * K + k0) << 1) + cbt;
            const char* sb = (const char*)Wt + (((size_t)(bn + r) * K + k0) << 1) + cbt;
            __builtin_amdgcn_global_load_lds((const void*)sa, (void*)(&As[0][0] + c * 512), 16, 0, 0);
            __builtin_amdgcn_global_load_lds((const void*)sb, (void*)(&Bs[0][0] + c * 512), 16, 0, 0);
        }
        __syncthreads();
        #pragma unroll
        for (int kk = 0; kk < 64; kk += 32) {
            bf16x8 af[4], bfr[4];
            #pragma unroll
            for (int m = 0; m < 4; ++m)
                af[m] = *(const bf16x8*)&As[wm + m * 16 + lr][kk + lh * 8];
            #pragma unroll
            for (int n = 0; n < 4; ++n)
                bfr[n] = *(const bf16x8*)&Bs[wn + n * 16 + lr][kk + lh * 8];
            #pragma unroll
            for (int m = 0; m < 4; ++m)
                #pragma unroll
                for (int n = 0; n < 4; ++n)
                    acc[m][n] = __builtin_amdgcn_mfma_f32_16x16x32_bf16(
                        af[m], bfr[n], acc[m][n], 0, 0, 0);
        }
    }

    #pragma unroll
    for (int n = 0; n < 4; ++n) {
        const int col = bn + wn + n * 16 + lr;
        const float bcol = bias[col];
        #pragma unroll
        for (int m = 0; m < 4; ++m) {
            #pragma unroll
            for (int i = 0; i < 4; ++i) {
                const int row = bm + wm + m * 16 + lh * 4 + i;
                float v = acc[m][n][i] + bcol;
                if (RELU) v = fmaxf(v, 0.f);
                if (OUTF32) ((float*)C)[(size_t)row * N + col] = v;
                else        ((ushort*)C)[(size_t)row * N + col] = f2bf(v);
            }
        }
    }
}

// ---- distinctly-named kernel wrappers (per-layer profiler attribution) ----
__global__ __launch_bounds__(256) void enc1_gemm(const float* A, const float* W, const float* b, float* C)
{ gemm_f32_dev<true>(A, W, b, C, 768, 2048); }
__global__ __launch_bounds__(256) void enc2_gemm(const float* A, const float* W, const float* b, float* C)
{ gemm_f32_dev<true>(A, W, b, C, 2048, 1024); }
__global__ __launch_bounds__(256) void enc3_gemm(const float* A, const float* W, const float* b, float* C)
{ gemm_f32_dev<true>(A, W, b, C, 1024, 512); }
__global__ __launch_bounds__(256) void enc4_gemm(const float* A, const float* W, const float* b, float* C)
{ gemm_f32_64_dev<false>(A, W, b, C, 512, 128); }
__global__ __launch_bounds__(256) void dec1_gemm(const ushort* A, const ushort* Wt, const float* b, void* C)
{ gemm_bf16_dev<true, false>(A, Wt, b, C, 128, 2048); }
__global__ __launch_bounds__(256) void dec2_gemm(const ushort* A, const ushort* Wt, const float* b, void* C)
{ gemm_bf16_dev<true, false>(A, Wt, b, C, 2048, 1024); }
__global__ __launch_bounds__(256) void dec3_gemm(const ushort* A, const ushort* Wt, const float* b, void* C)
{ gemm_bf16_dev<true, false>(A, Wt, b, C, 1024, 512); }
__global__ __launch_bounds__(256) void dec4_gemm(const ushort* A, const ushort* Wt, const float* b, void* C)
{ gemm_bf16_dev<false, true>(A, Wt, b, C, 512, 768); }

// ---------------- weight convert+transpose: W[K][N] f32 -> Wt[N][K] bf16 ----
__global__ __launch_bounds__(256) void wt_convert(
    const float* __restrict__ W, ushort* __restrict__ Wt, int K, int N)
{
    __shared__ ushort t[64][65];
    const int kb = blockIdx.y << 6, nb = blockIdx.x << 6;
    const int c  = threadIdx.x & 63;
    const int r0 = (threadIdx.x >> 6) << 4;
    #pragma unroll
    for (int i = 0; i < 16; ++i)
        t[r0 + i][c] = f2bf(W[(size_t)(kb + r0 + i) * N + nb + c]);
    __syncthreads();
    #pragma unroll
    for (int i = 0; i < 16; ++i)
        Wt[(size_t)(nb + r0 + i) * K + kb + c] = t[c][r0 + i];
}

// ---------------- codebook squared norms ----------------
__global__ __launch_bounds__(256) void cbsq_kernel(
    const float* __restrict__ cb, float* __restrict__ cbsq)
{
    int k = blockIdx.x * 256 + threadIdx.x;
    const float* r = cb + ((size_t)k << 7);
    float s = 0.f;
    #pragma unroll 8
    for (int d = 0; d < 128; ++d) s = fmaf(r[d], r[d], s);
    cbsq[k] = s;
}

// ---------------- residual quantization v4: lane-pair rows ----------------
// Block = 256 thr = 4 waves, 64 rows. Each row lives on a LANE PAIR
// (half = lane&1, 64 VGPRs of residue per lane -> no spill).
// Waves {0,1} hold rows {0-31,32-63} scanning codes [0,512);
// waves {2,3} duplicate the rows scanning [512,1024). LDS merge = first-min.
// Codebook chunks staged to wave-private LDS via global_load_lds, dbuf,
// counted vmcnt(8).
__global__ __launch_bounds__(256, 2) void rq_quant(
    const float* __restrict__ z, const float* __restrict__ cb,
    const float* __restrict__ cbsq, ushort* __restrict__ zhat_bf,
    float* __restrict__ codes)
{
    __shared__ __align__(16) float cbl[2][4][16 * 128];  // 64 KiB
    __shared__ float sd[4][64];
    __shared__ int   si[4][64];
    __shared__ int   sbi[64];

    const int lane = threadIdx.x & 63;
    const int wv   = threadIdx.x >> 6;
    const int half = lane & 1;
    const int rib  = ((wv & 1) << 5) + (lane >> 1);   // row in block 0..63
    const size_t row = (size_t)blockIdx.x * 64 + rib;
    const int kbeg = (wv >> 1) << 9;                  // 0 or 512

    const float4* zr = (const float4*)(z + row * 128) + half * 16;
    float4 r[16];
    #pragma unroll
    for (int i = 0; i < 16; ++i) r[i] = zr[i];

    // cbsq for this wave's 512 codes, 8 per lane (served via shuffle)
    float mycb[8];
    #pragma unroll
    for (int j = 0; j < 8; ++j) mycb[j] = cbsq[kbeg + (j << 6) + lane];

    auto stage = [&](int c, int b) {   // chunk c (16 codes) -> buffer b
        const float* src = cb + ((size_t)(kbeg + (c << 4)) << 7);
        float* dst = &cbl[b][wv][0];
        #pragma unroll
        for (int i = 0; i < 8; ++i) {
            __builtin_amdgcn_global_load_lds(
                (const void*)(src + i * 256 + lane * 4),
                (void*)(dst + i * 256), 16, 0, 0);
        }
    };

    for (int t = 0; t < 3; ++t) {
        float4 rr4 = {0.f, 0.f, 0.f, 0.f};
        #pragma unroll
        for (int i = 0; i < 16; ++i) {
            rr4.x = fmaf(r[i].x, r[i].x, rr4.x);
            rr4.y = fmaf(r[i].y, r[i].y, rr4.y);
            rr4.z = fmaf(r[i].z, r[i].z, rr4.z);
            rr4.w = fmaf(r[i].w, r[i].w, rr4.w);
        }
        float rrh = (rr4.x + rr4.y) + (rr4.z + rr4.w);
        const float rr = rrh + __shfl_xor(rrh, 1);

        stage(0, 0);
        float bd = FLT_MAX_C; int bi = 0;
        for (int c = 0; c < 32; ++c) {
            if (c < 31) {
                stage(c + 1, (c + 1) & 1);
                asm volatile("s_waitcnt vmcnt(8)" ::: "memory");
            } else {
                asm volatile("s_waitcnt vmcnt(0)" ::: "memory");
            }
            const float* buf = cbl[c & 1][wv] + half * 64;
            #pragma unroll 4
            for (int tt = 0; tt < 16; ++tt) {
                const float4* c4 = (const float4*)(buf + tt * 128);
                float4 a4 = {0.f, 0.f, 0.f, 0.f};
                #pragma unroll
                for (int i = 0; i < 16; ++i) {
                    float4 cv = c4[i];
                    a4.x = fmaf(r[i].x, cv.x, a4.x);
                    a4.y = fmaf(r[i].y, cv.y, a4.y);
                    a4.z = fmaf(r[i].z, cv.z, a4.z);
                    a4.w = fmaf(r[i].w, cv.w, a4.w);
                }
                float dh = (a4.x + a4.y) + (a4.z + a4.w);
                float dot = dh + __shfl_xor(dh, 1);
                const int q = (c << 4) + tt;
                float cs = __shfl(mycb[q >> 6], q & 63);
                float dist = (rr + cs) - 2.f * dot;
                if (dist < bd) { bd = dist; bi = kbeg + q; }
            }
        }
        sd[wv][rib] = bd; si[wv][rib] = bi;   // both halves write same value
        __syncthreads();
        if (threadIdx.x < 64) {
            const int rr_ = threadIdx.x;
            const int w0 = (rr_ < 32) ? 0 : 1;
            float d = sd[w0][rr_]; int b = si[w0][rr_];
            float d2 = sd[w0 + 2][rr_]; int b2 = si[w0 + 2][rr_];
            if (d2 < d) { d = d2; b = b2; }   // strict: lower range wins ties
            sbi[rr_] = b;
            codes[((size_t)blockIdx.x * 64 + rr_) * 3 + t] = (float)b;
        }
        __syncthreads();
        const int bidx = sbi[rib];
        const float4* cbest = (const float4*)(cb + ((size_t)bidx << 7)) + half * 16;
        #pragma unroll
        for (int i = 0; i < 16; ++i) {
            float4 cv = cbest[i];
            r[i].x -= cv.x; r[i].y -= cv.y; r[i].z -= cv.z; r[i].w -= cv.w;
        }
    }

    // zhat = z - r_final; waves 0,1 cover all 64 rows x both halves
    if (wv < 2) {
        ushort* zrow = zhat_bf + row * 128 + half * 64;
        #pragma unroll
        for (int i = 0; i < 16; ++i) {
            float4 zv = zr[i];
            ushort4 o;
            o.x = f2bf(zv.x - r[i].x); o.y = f2bf(zv.y - r[i].y);
            o.z = f2bf(zv.z - r[i].z); o.w = f2bf(zv.w - r[i].w);
            ((ushort4*)zrow)[i] = o;
        }
    }
}

extern "C" void kernel_launch(void* const* d_in, const int* in_sizes, int n_in,
                              void* d_out, int out_size, void* d_ws, size_t ws_size,
                              hipStream_t stream)
{
    const float* x   = (const float*)d_in[0];
    const float* eW1 = (const float*)d_in[1];
    const float* eb1 = (const float*)d_in[2];
    const float* eW2 = (const float*)d_in[3];
    const float* eb2 = (const float*)d_in[4];
    const float* eW3 = (const float*)d_in[5];
    const float* eb3 = (const float*)d_in[6];
    const float* eW4 = (const float*)d_in[7];
    const float* eb4 = (const float*)d_in[8];
    const float* dW1 = (const float*)d_in[9];
    const float* db1 = (const float*)d_in[10];
    const float* dW2 = (const float*)d_in[11];
    const float* db2 = (const float*)d_in[12];
    const float* dW3 = (const float*)d_in[13];
    const float* db3 = (const float*)d_in[14];
    const float* dW4 = (const float*)d_in[15];
    const float* db4 = (const float*)d_in[16];
    const float* cb  = (const float*)d_in[17];

    float* out   = (float*)d_out;
    float* codes = out + (size_t)32768 * 768;

    // ---- workspace: [dec Wt bf16 | cbsq | per-chunk activations] ----
    ushort* Wt1 = (ushort*)d_ws;                       // 2048 x 128
    ushort* Wt2 = Wt1 + (size_t)2048 * 128;            // 1024 x 2048
    ushort* Wt3 = Wt2 + (size_t)1024 * 2048;           // 512 x 1024
    ushort* Wt4 = Wt3 + (size_t)512 * 1024;            // 768 x 512
    float*  sq  = (float*)(Wt4 + (size_t)768 * 512);   // 1024
    float*  act = sq + 1024;
    const size_t fixed_b = (char*)act - (char*)d_ws;

    int mc = 32768;
    while (mc > 1024) {
        if (fixed_b + (size_t)mc * 15104 <= ws_size) break;
        mc >>= 1;
    }

    float*  R1  = act;                         // mc x 2048 f32
    float*  R2  = R1 + (size_t)mc * 2048;      // mc x 1024 f32
    float*  R3  = R2 + (size_t)mc * 1024;      // mc x 512  f32
    float*  RZ  = R3 + (size_t)mc * 512;       // mc x 128  f32
    ushort* ZHb = (ushort*)(RZ + (size_t)mc * 128);  // mc x 128 bf16
    ushort* D1  = (ushort*)R1;                 // bf16 aliases
    ushort* D2  = (ushort*)R2;
    ushort* D3  = (ushort*)R3;

    wt_convert<<<dim3(2048 / 64, 128 / 64), 256, 0, stream>>>(dW1, Wt1, 128, 2048);
    wt_convert<<<dim3(1024 / 64, 2048 / 64), 256, 0, stream>>>(dW2, Wt2, 2048, 1024);
    wt_convert<<<dim3(512 / 64, 1024 / 64), 256, 0, stream>>>(dW3, Wt3, 1024, 512);
    wt_convert<<<dim3(768 / 64, 512 / 64), 256, 0, stream>>>(dW4, Wt4, 512, 768);
    cbsq_kernel<<<4, 256, 0, stream>>>(cb, sq);

    const int mg = mc >> 7;
    for (int r0 = 0; r0 < 32768; r0 += mc) {
        const float* xi     = x     + (size_t)r0 * 768;
        float*       outi   = out   + (size_t)r0 * 768;
        float*       codesi = codes + (size_t)r0 * 3;
        // encoder (fp32 exact-class: codes depend on z)
        enc1_gemm<<<dim3(16, mg), 256, 0, stream>>>(xi, eW1, eb1, R1);
        enc2_gemm<<<dim3( 8, mg), 256, 0, stream>>>(R1, eW2, eb2, R2);
        enc3_gemm<<<dim3( 4, mg), 256, 0, stream>>>(R2, eW3, eb3, R3);
        enc4_gemm<<<dim3( 1, mc >> 6), 256, 0, stream>>>(R3, eW4, eb4, RZ);
        // residual quantization (fp32 exact formula), emits bf16 z_hat
        rq_quant<<<mc >> 6, 256, 0, stream>>>(RZ, cb, sq, ZHb, codesi);
        // decoder in bf16 MFMA
        dec1_gemm<<<dim3(16, mg), 256, 0, stream>>>(ZHb, Wt1, db1, D1);
        dec2_gemm<<<dim3( 8, mg), 256, 0, stream>>>(D1,  Wt2, db2, D2);
        dec3_gemm<<<dim3( 4, mg), 256, 0, stream>>>(D2,  Wt3, db3, D3);
        dec4_gemm<<<dim3( 6, mg), 256, 0, stream>>>(D3,  Wt4, db4, outi);
    }
}

// Round 8
// 4009.964 us; speedup vs baseline: 1.3522x; 1.3522x over previous
//
#include <hip/hip_runtime.h>

#define FLT_MAX_C 3.402823466e+38f

typedef __attribute__((ext_vector_type(8))) __bf16 bf16x8;
typedef __attribute__((ext_vector_type(4))) float f32x4;

static __device__ __forceinline__ ushort f2bf(float x) {
    union { float f; unsigned u; } v; v.f = x;
    unsigned r = (v.u + 0x7FFFu + ((v.u >> 16) & 1u)) >> 16;
    return (ushort)r;
}

// ================= fp32 GEMM body (R3/R5-proven: BK=8, 128x128) ==========
template<bool RELU>
__device__ __forceinline__ void gemm_f32_dev(
    const float* __restrict__ A, const float* __restrict__ W,
    const float* __restrict__ bias, float* __restrict__ C, int K, int N)
{
    __shared__ float As[8][128];
    __shared__ float Bs[8][132];
    const int tid = threadIdx.x;
    const int bm = blockIdx.y << 7;
    const int bn = blockIdx.x << 7;

    const int la_row = tid >> 1;
    const int la_k   = (tid & 1) << 2;
    const int lb_row = tid >> 5;
    const int lb_col = (tid & 31) << 2;
    const int tm4 = (tid >> 4) << 2;
    const int tn4 = (tid & 15) << 2;

    float acc[8][8];
    #pragma unroll
    for (int i = 0; i < 8; ++i)
        #pragma unroll
        for (int j = 0; j < 8; ++j) acc[i][j] = 0.f;

    const float* aptr = A + (size_t)(bm + la_row) * K + la_k;
    const float* bptr = W + (size_t)lb_row * N + bn + lb_col;

    float4 av = *(const float4*)(aptr);
    float4 bv = *(const float4*)(bptr);

    for (int k0 = 0; k0 < K; k0 += 8) {
        __syncthreads();
        As[la_k + 0][la_row] = av.x;
        As[la_k + 1][la_row] = av.y;
        As[la_k + 2][la_row] = av.z;
        As[la_k + 3][la_row] = av.w;
        *(float4*)(&Bs[lb_row][lb_col]) = bv;
        __syncthreads();
        if (k0 + 8 < K) {
            av = *(const float4*)(aptr + k0 + 8);
            bv = *(const float4*)(bptr + (size_t)(k0 + 8) * N);
        }
        #pragma unroll
        for (int kk = 0; kk < 8; ++kk) {
            float a[8], b[8];
            *(float4*)(a)     = *(const float4*)(&As[kk][tm4]);
            *(float4*)(a + 4) = *(const float4*)(&As[kk][tm4 + 64]);
            *(float4*)(b)     = *(const float4*)(&Bs[kk][tn4]);
            *(float4*)(b + 4) = *(const float4*)(&Bs[kk][tn4 + 64]);
            #pragma unroll
            for (int i = 0; i < 8; ++i)
                #pragma unroll
                for (int j = 0; j < 8; ++j)
                    acc[i][j] = fmaf(a[i], b[j], acc[i][j]);
        }
    }

    float bv0[8];
    #pragma unroll
    for (int j = 0; j < 8; ++j)
        bv0[j] = bias[bn + tn4 + (j < 4 ? j : 60 + j)];

    #pragma unroll
    for (int i = 0; i < 8; ++i) {
        int row = bm + tm4 + (i < 4 ? i : 60 + i);
        float* cp = C + (size_t)row * N + bn + tn4;
        float4 v0, v1;
        v0.x = acc[i][0] + bv0[0]; v0.y = acc[i][1] + bv0[1];
        v0.z = acc[i][2] + bv0[2]; v0.w = acc[i][3] + bv0[3];
        v1.x = acc[i][4] + bv0[4]; v1.y = acc[i][5] + bv0[5];
        v1.z = acc[i][6] + bv0[6]; v1.w = acc[i][7] + bv0[7];
        if (RELU) {
            v0.x = fmaxf(v0.x, 0.f); v0.y = fmaxf(v0.y, 0.f);
            v0.z = fmaxf(v0.z, 0.f); v0.w = fmaxf(v0.w, 0.f);
            v1.x = fmaxf(v1.x, 0.f); v1.y = fmaxf(v1.y, 0.f);
            v1.z = fmaxf(v1.z, 0.f); v1.w = fmaxf(v1.w, 0.f);
        }
        *(float4*)(cp) = v0;
        *(float4*)(cp + 64) = v1;
    }
}

// ========== fp32 GEMM small-M body (BM=64, BN=128, BK=16) for enc4 ==========
template<bool RELU>
__device__ __forceinline__ void gemm_f32_64_dev(
    const float* __restrict__ A, const float* __restrict__ W,
    const float* __restrict__ bias, float* __restrict__ C, int K, int N)
{
    __shared__ float As[16][64];
    __shared__ float Bs[16][132];
    const int tid = threadIdx.x;
    const int bm = blockIdx.y << 6;
    const int bn = blockIdx.x << 7;

    const int la_row = tid & 63;
    const int la_k   = (tid >> 6) << 2;
    const int lb_row = tid >> 5;
    const int lb_col = (tid & 31) << 2;
    const int tr = tid >> 4;
    const int tc = tid & 15;

    float acc[4][8];
    #pragma unroll
    for (int i = 0; i < 4; ++i)
        #pragma unroll
        for (int j = 0; j < 8; ++j) acc[i][j] = 0.f;

    const float* aptr = A + (size_t)(bm + la_row) * K + la_k;
    const float* bptr = W + (size_t)lb_row * N + bn + lb_col;

    float4 av = *(const float4*)(aptr);
    float4 bv0 = *(const float4*)(bptr);
    float4 bv1 = *(const float4*)(bptr + (size_t)8 * N);

    for (int k0 = 0; k0 < K; k0 += 16) {
        __syncthreads();
        As[la_k + 0][la_row] = av.x;
        As[la_k + 1][la_row] = av.y;
        As[la_k + 2][la_row] = av.z;
        As[la_k + 3][la_row] = av.w;
        *(float4*)(&Bs[lb_row][lb_col]) = bv0;
        *(float4*)(&Bs[lb_row + 8][lb_col]) = bv1;
        __syncthreads();
        if (k0 + 16 < K) {
            av  = *(const float4*)(aptr + k0 + 16);
            bv0 = *(const float4*)(bptr + (size_t)(k0 + 16) * N);
            bv1 = *(const float4*)(bptr + (size_t)(k0 + 24) * N);
        }
        #pragma unroll
        for (int kk = 0; kk < 16; ++kk) {
            float a[4], b[8];
            *(float4*)(a) = *(const float4*)(&As[kk][tr << 2]);
            *(float4*)(b)     = *(const float4*)(&Bs[kk][tc << 2]);
            *(float4*)(b + 4) = *(const float4*)(&Bs[kk][(tc << 2) + 64]);
            #pragma unroll
            for (int i = 0; i < 4; ++i)
                #pragma unroll
                for (int j = 0; j < 8; ++j)
                    acc[i][j] = fmaf(a[i], b[j], acc[i][j]);
        }
    }

    float bb[8];
    #pragma unroll
    for (int j = 0; j < 8; ++j)
        bb[j] = bias[bn + (tc << 2) + (j < 4 ? j : 60 + j)];

    #pragma unroll
    for (int i = 0; i < 4; ++i) {
        float* cp = C + (size_t)(bm + (tr << 2) + i) * N + bn + (tc << 2);
        float4 v0, v1;
        v0.x = acc[i][0] + bb[0]; v0.y = acc[i][1] + bb[1];
        v0.z = acc[i][2] + bb[2]; v0.w = acc[i][3] + bb[3];
        v1.x = acc[i][4] + bb[4]; v1.y = acc[i][5] + bb[5];
        v1.z = acc[i][6] + bb[6]; v1.w = acc[i][7] + bb[7];
        if (RELU) {
            v0.x = fmaxf(v0.x, 0.f); v0.y = fmaxf(v0.y, 0.f);
            v0.z = fmaxf(v0.z, 0.f); v0.w = fmaxf(v0.w, 0.f);
            v1.x = fmaxf(v1.x, 0.f); v1.y = fmaxf(v1.y, 0.f);
            v1.z = fmaxf(v1.z, 0.f); v1.w = fmaxf(v1.w, 0.f);
        }
        *(float4*)(cp) = v0;
        *(float4*)(cp + 64) = v1;
    }
}

// ================= bf16 MFMA GEMM device body (decoder) =================
template<bool RELU, bool OUTF32>
__device__ __forceinline__ void gemm_bf16_dev(
    const ushort* __restrict__ A, const ushort* __restrict__ Wt,
    const float* __restrict__ bias, void* __restrict__ C, int K, int N)
{
    __shared__ __align__(16) ushort As[128][64];
    __shared__ __align__(16) ushort Bs[128][64];
    const int tid  = threadIdx.x;
    const int lane = tid & 63;
    const int wv   = tid >> 6;
    const int wm   = (wv >> 1) << 6;
    const int wn   = (wv & 1) << 6;
    const int bm   = blockIdx.y << 7;
    const int bn   = blockIdx.x << 7;
    const int lr   = lane & 15;
    const int lh   = lane >> 4;

    f32x4 acc[4][4];
    #pragma unroll
    for (int m = 0; m < 4; ++m)
        #pragma unroll
        for (int n = 0; n < 4; ++n) acc[m][n] = (f32x4){0.f, 0.f, 0.f, 0.f};

    for (int k0 = 0; k0 < K; k0 += 64) {
        __syncthreads();
        #pragma unroll
        for (int i = 0; i < 4; ++i) {
            const int c    = wv * 4 + i;
            const int boff = c * 1024 + lane * 16;
            const int r    = boff >> 7;
            const int cbt  = boff & 127;
            const char* sa = (const char*)A  + (((size_t)(bm + r) * K + k0) << 1) + cbt;
            const char* sb = (const char*)Wt + (((size_t)(bn + r) * K + k0) << 1) + cbt;
            __builtin_amdgcn_global_load_lds((const void*)sa, (void*)(&As[0][0] + c * 512), 16, 0, 0);
            __builtin_amdgcn_global_load_lds((const void*)sb, (void*)(&Bs[0][0] + c * 512), 16, 0, 0);
        }
        __syncthreads();
        #pragma unroll
        for (int kk = 0; kk < 64; kk += 32) {
            bf16x8 af[4], bfr[4];
            #pragma unroll
            for (int m = 0; m < 4; ++m)
                af[m] = *(const bf16x8*)&As[wm + m * 16 + lr][kk + lh * 8];
            #pragma unroll
            for (int n = 0; n < 4; ++n)
                bfr[n] = *(const bf16x8*)&Bs[wn + n * 16 + lr][kk + lh * 8];
            #pragma unroll
            for (int m = 0; m < 4; ++m)
                #pragma unroll
                for (int n = 0; n < 4; ++n)
                    acc[m][n] = __builtin_amdgcn_mfma_f32_16x16x32_bf16(
                        af[m], bfr[n], acc[m][n], 0, 0, 0);
        }
    }

    #pragma unroll
    for (int n = 0; n < 4; ++n) {
        const int col = bn + wn + n * 16 + lr;
        const float bcol = bias[col];
        #pragma unroll
        for (int m = 0; m < 4; ++m) {
            #pragma unroll
            for (int i = 0; i < 4; ++i) {
                const int row = bm + wm + m * 16 + lh * 4 + i;
                float v = acc[m][n][i] + bcol;
                if (RELU) v = fmaxf(v, 0.f);
                if (OUTF32) ((float*)C)[(size_t)row * N + col] = v;
                else        ((ushort*)C)[(size_t)row * N + col] = f2bf(v);
            }
        }
    }
}

// ---- named wrappers ----
__global__ __launch_bounds__(256) void enc1_gemm(const float* A, const float* W, const float* b, float* C)
{ gemm_f32_dev<true>(A, W, b, C, 768, 2048); }
__global__ __launch_bounds__(256) void enc2_gemm(const float* A, const float* W, const float* b, float* C)
{ gemm_f32_dev<true>(A, W, b, C, 2048, 1024); }
__global__ __launch_bounds__(256) void enc3_gemm(const float* A, const float* W, const float* b, float* C)
{ gemm_f32_dev<true>(A, W, b, C, 1024, 512); }
__global__ __launch_bounds__(256) void enc4_gemm(const float* A, const float* W, const float* b, float* C)
{ gemm_f32_64_dev<false>(A, W, b, C, 512, 128); }
__global__ __launch_bounds__(256) void dec1_gemm(const ushort* A, const ushort* Wt, const float* b, void* C)
{ gemm_bf16_dev<true, false>(A, Wt, b, C, 128, 2048); }
__global__ __launch_bounds__(256) void dec2_gemm(const ushort* A, const ushort* Wt, const float* b, void* C)
{ gemm_bf16_dev<true, false>(A, Wt, b, C, 2048, 1024); }
__global__ __launch_bounds__(256) void dec3_gemm(const ushort* A, const ushort* Wt, const float* b, void* C)
{ gemm_bf16_dev<true, false>(A, Wt, b, C, 1024, 512); }
__global__ __launch_bounds__(256) void dec4_gemm(const ushort* A, const ushort* Wt, const float* b, void* C)
{ gemm_bf16_dev<false, true>(A, Wt, b, C, 512, 768); }

// ---------------- weight convert+transpose: W[K][N] f32 -> Wt[N][K] bf16 ----
__global__ __launch_bounds__(256) void wt_convert(
    const float* __restrict__ W, ushort* __restrict__ Wt, int K, int N)
{
    __shared__ ushort t[64][65];
    const int kb = blockIdx.y << 6, nb = blockIdx.x << 6;
    const int c  = threadIdx.x & 63;
    const int r0 = (threadIdx.x >> 6) << 4;
    #pragma unroll
    for (int i = 0; i < 16; ++i)
        t[r0 + i][c] = f2bf(W[(size_t)(kb + r0 + i) * N + nb + c]);
    __syncthreads();
    #pragma unroll
    for (int i = 0; i < 16; ++i)
        Wt[(size_t)(nb + r0 + i) * K + kb + c] = t[c][r0 + i];
}

// ---------------- codebook prep ----------------
__global__ __launch_bounds__(256) void cbsq_kernel(
    const float* __restrict__ cb, float* __restrict__ cbsq)
{
    int k = blockIdx.x * 256 + threadIdx.x;
    const float* r = cb + ((size_t)k << 7);
    float s = 0.f;
    #pragma unroll 8
    for (int d = 0; d < 128; ++d) s = fmaf(r[d], r[d], s);
    cbsq[k] = s;
}

// cbt[d][k] = cb[k][d] : [128][1024] f32.  grid (16, 2)
__global__ __launch_bounds__(256) void cbt_kernel(
    const float* __restrict__ cb, float* __restrict__ cbt)
{
    __shared__ float t[64][65];
    const int kb = blockIdx.x << 6;
    const int db = blockIdx.y << 6;
    const int c  = threadIdx.x & 63;
    const int r0 = (threadIdx.x >> 6) << 4;
    #pragma unroll
    for (int i = 0; i < 16; ++i)
        t[r0 + i][c] = cb[(size_t)(kb + r0 + i) * 128 + db + c];
    __syncthreads();
    #pragma unroll
    for (int i = 0; i < 16; ++i)
        cbt[(size_t)(db + r0 + i) * 1024 + kb + c] = t[c][r0 + i];
}

// ---------------- fused RQ depth step ----------------
// One kernel per depth T. Block owns 64 rows: dist-GEMM over all 1024 codes
// (8 col-tiles, BK=16), running first-min per thread, 16-lane tie-break
// reduce, then block-local state update (codes, ZH += cb[best], RR = z - ZH).
// No cross-kernel scratch except ZH/RR rows owned exclusively by this block.
template<int T>
__global__ __launch_bounds__(256) void rq_step(
    const float* __restrict__ Rres, const float* __restrict__ cbt,
    const float* __restrict__ sq, const float* __restrict__ cb,
    const float* __restrict__ z, float* __restrict__ ZH,
    float* __restrict__ RR, ushort* __restrict__ ZHb,
    float* __restrict__ codes)
{
    __shared__ float As[16][64];
    __shared__ float Bs[16][132];
    __shared__ float rrp[4][64];
    __shared__ float rrs[64];

    const int tid = threadIdx.x;
    const int bm = blockIdx.x << 6;

    const int la_row = tid & 63;
    const int la_k   = (tid >> 6) << 2;   // 0,4,8,12
    const int lb_row = tid >> 5;          // 0..7 (+8)
    const int lb_col = (tid & 31) << 2;
    const int tr  = tid >> 4;             // group id: rows tr*4..+3
    const int tn4 = (tid & 15) << 2;

    // ---- row squared norms (block-local) ----
    {
        const int r_ = tid & 63, seg = tid >> 6;
        const float4* rp = (const float4*)(Rres + (size_t)(bm + r_) * 128) + seg * 8;
        float s = 0.f;
        #pragma unroll
        for (int i = 0; i < 8; ++i) {
            float4 v = rp[i];
            s = fmaf(v.x, v.x, s); s = fmaf(v.y, v.y, s);
            s = fmaf(v.z, v.z, s); s = fmaf(v.w, v.w, s);
        }
        rrp[seg][r_] = s;
    }
    __syncthreads();
    if (tid < 64) rrs[tid] = (rrp[0][tid] + rrp[1][tid]) + (rrp[2][tid] + rrp[3][tid]);
    __syncthreads();

    float rr_[4];
    #pragma unroll
    for (int i = 0; i < 4; ++i) rr_[i] = rrs[(tr << 2) + i];

    float best_d[4] = {FLT_MAX_C, FLT_MAX_C, FLT_MAX_C, FLT_MAX_C};
    int   best_i[4] = {0, 0, 0, 0};

    const float* aptr = Rres + (size_t)(bm + la_row) * 128 + la_k;

    for (int bx = 0; bx < 8; ++bx) {
        const int bn = bx << 7;
        float acc[4][8];
        #pragma unroll
        for (int i = 0; i < 4; ++i)
            #pragma unroll
            for (int j = 0; j < 8; ++j) acc[i][j] = 0.f;

        const float* bptr = cbt + (size_t)lb_row * 1024 + bn + lb_col;
        float4 av  = *(const float4*)(aptr);
        float4 bv0 = *(const float4*)(bptr);
        float4 bv1 = *(const float4*)(bptr + (size_t)8 * 1024);

        for (int k0 = 0; k0 < 128; k0 += 16) {
            __syncthreads();
            As[la_k + 0][la_row] = av.x;
            As[la_k + 1][la_row] = av.y;
            As[la_k + 2][la_row] = av.z;
            As[la_k + 3][la_row] = av.w;
            *(float4*)(&Bs[lb_row][lb_col]) = bv0;
            *(float4*)(&Bs[lb_row + 8][lb_col]) = bv1;
            __syncthreads();
            if (k0 + 16 < 128) {
                av  = *(const float4*)(aptr + k0 + 16);
                bv0 = *(const float4*)(bptr + (size_t)(k0 + 16) * 1024);
                bv1 = *(const float4*)(bptr + (size_t)(k0 + 24) * 1024);
            }
            #pragma unroll
            for (int kk = 0; kk < 16; ++kk) {
                float a[4], b[8];
                *(float4*)(a) = *(const float4*)(&As[kk][tr << 2]);
                *(float4*)(b)     = *(const float4*)(&Bs[kk][tn4]);
                *(float4*)(b + 4) = *(const float4*)(&Bs[kk][tn4 + 64]);
                #pragma unroll
                for (int i = 0; i < 4; ++i)
                    #pragma unroll
                    for (int j = 0; j < 8; ++j)
                        acc[i][j] = fmaf(a[i], b[j], acc[i][j]);
            }
        }
        // running first-min compare (cols ascending: bx outer, j inner)
        #pragma unroll
        for (int i = 0; i < 4; ++i) {
            #pragma unroll
            for (int j = 0; j < 8; ++j) {
                const int col = bn + tn4 + (j < 4 ? j : 60 + j);
                float d = (rr_[i] + sq[col]) - 2.f * acc[i][j];
                if (d < best_d[i]) { best_d[i] = d; best_i[i] = col; }
            }
        }
    }

    // ---- final reduce + state update (block-local rows) ----
    #pragma unroll
    for (int i = 0; i < 4; ++i) {
        float bd = best_d[i]; int bi = best_i[i];
        #pragma unroll
        for (int o = 8; o >= 1; o >>= 1) {
            float od = __shfl_xor(bd, o);
            int   oi = __shfl_xor(bi, o);
            if (od < bd || (od == bd && oi < bi)) { bd = od; bi = oi; }
        }
        const int row = bm + (tr << 2) + i;
        if ((tid & 15) == 0) codes[(size_t)row * 3 + T] = (float)bi;

        const int d8 = (tid & 15) << 3;
        const float* cbp = cb + ((size_t)bi << 7) + d8;
        float4 c0 = *(const float4*)(cbp);
        float4 c1 = *(const float4*)(cbp + 4);
        float4 zh0, zh1;
        if (T == 0) {
            zh0 = c0; zh1 = c1;
        } else {
            const float* zhp = ZH + (size_t)row * 128 + d8;
            float4 p0 = *(const float4*)(zhp);
            float4 p1 = *(const float4*)(zhp + 4);
            zh0.x = p0.x + c0.x; zh0.y = p0.y + c0.y;
            zh0.z = p0.z + c0.z; zh0.w = p0.w + c0.w;
            zh1.x = p1.x + c1.x; zh1.y = p1.y + c1.y;
            zh1.z = p1.z + c1.z; zh1.w = p1.w + c1.w;
        }
        if (T < 2) {
            float* zhp = ZH + (size_t)row * 128 + d8;
            *(float4*)(zhp)     = zh0;
            *(float4*)(zhp + 4) = zh1;
            const float* zp = z + (size_t)row * 128 + d8;
            float4 z0 = *(const float4*)(zp);
            float4 z1 = *(const float4*)(zp + 4);
            float4 r0, r1;
            r0.x = z0.x - zh0.x; r0.y = z0.y - zh0.y;
            r0.z = z0.z - zh0.z; r0.w = z0.w - zh0.w;
            r1.x = z1.x - zh1.x; r1.y = z1.y - zh1.y;
            r1.z = z1.z - zh1.z; r1.w = z1.w - zh1.w;
            float* rp = RR + (size_t)row * 128 + d8;
            *(float4*)(rp)     = r0;
            *(float4*)(rp + 4) = r1;
        } else {
            ushort4 o0, o1;
            o0.x = f2bf(zh0.x); o0.y = f2bf(zh0.y);
            o0.z = f2bf(zh0.z); o0.w = f2bf(zh0.w);
            o1.x = f2bf(zh1.x); o1.y = f2bf(zh1.y);
            o1.z = f2bf(zh1.z); o1.w = f2bf(zh1.w);
            ushort* zbp = ZHb + (size_t)row * 128 + d8;
            *(ushort4*)(zbp)     = o0;
            *(ushort4*)(zbp + 4) = o1;
        }
    }
}

extern "C" void kernel_launch(void* const* d_in, const int* in_sizes, int n_in,
                              void* d_out, int out_size, void* d_ws, size_t ws_size,
                              hipStream_t stream)
{
    const float* x   = (const float*)d_in[0];
    const float* eW1 = (const float*)d_in[1];
    const float* eb1 = (const float*)d_in[2];
    const float* eW2 = (const float*)d_in[3];
    const float* eb2 = (const float*)d_in[4];
    const float* eW3 = (const float*)d_in[5];
    const float* eb3 = (const float*)d_in[6];
    const float* eW4 = (const float*)d_in[7];
    const float* eb4 = (const float*)d_in[8];
    const float* dW1 = (const float*)d_in[9];
    const float* db1 = (const float*)d_in[10];
    const float* dW2 = (const float*)d_in[11];
    const float* db2 = (const float*)d_in[12];
    const float* dW3 = (const float*)d_in[13];
    const float* db3 = (const float*)d_in[14];
    const float* dW4 = (const float*)d_in[15];
    const float* db4 = (const float*)d_in[16];
    const float* cb  = (const float*)d_in[17];

    float* out   = (float*)d_out;
    float* codes = out + (size_t)32768 * 768;

    // ---- fixed region: dec Wt bf16 | cbsq | CBt f32 ----
    ushort* Wt1 = (ushort*)d_ws;                       // 2048 x 128
    ushort* Wt2 = Wt1 + (size_t)2048 * 128;            // 1024 x 2048
    ushort* Wt3 = Wt2 + (size_t)1024 * 2048;           // 512 x 1024
    ushort* Wt4 = Wt3 + (size_t)512 * 1024;            // 768 x 512
    float*  sq  = (float*)(Wt4 + (size_t)768 * 512);   // 1024
    float*  cbt = sq + 1024;                           // 128 x 1024
    float*  act = cbt + (size_t)128 * 1024;
    const size_t fixed_b = (char*)act - (char*)d_ws;

    int mc = 32768;
    while (mc > 1024) {
        if (fixed_b + (size_t)mc * 15104 <= ws_size) break;
        mc >>= 1;
    }

    float*  R1  = act;                               // mc x 2048 f32
    float*  R2  = R1 + (size_t)mc * 2048;            // mc x 1024 f32
    float*  R3  = R2 + (size_t)mc * 1024;            // mc x 512  f32
    float*  RZ  = R3 + (size_t)mc * 512;             // mc x 128  f32 (z)
    ushort* ZHb = (ushort*)(RZ + (size_t)mc * 128);  // mc x 128 bf16
    // RR/ZH live in the tail halves of R2/R3 that neither the encoder
    // (done before quant) nor the decoder (D2/D3 use only the head halves
    // as bf16) ever touches:
    float*  RR  = R2 + (size_t)mc * 512;             // mc x 128 f32
    float*  ZH  = R3 + (size_t)mc * 256;             // mc x 128 f32
    ushort* D1  = (ushort*)R1;
    ushort* D2  = (ushort*)R2;
    ushort* D3  = (ushort*)R3;

    wt_convert<<<dim3(2048 / 64, 128 / 64), 256, 0, stream>>>(dW1, Wt1, 128, 2048);
    wt_convert<<<dim3(1024 / 64, 2048 / 64), 256, 0, stream>>>(dW2, Wt2, 2048, 1024);
    wt_convert<<<dim3(512 / 64, 1024 / 64), 256, 0, stream>>>(dW3, Wt3, 1024, 512);
    wt_convert<<<dim3(768 / 64, 512 / 64), 256, 0, stream>>>(dW4, Wt4, 512, 768);
    cbsq_kernel<<<4, 256, 0, stream>>>(cb, sq);
    cbt_kernel<<<dim3(16, 2), 256, 0, stream>>>(cb, cbt);

    const int mg = mc >> 7;
    for (int r0 = 0; r0 < 32768; r0 += mc) {
        const float* xi     = x     + (size_t)r0 * 768;
        float*       outi   = out   + (size_t)r0 * 768;
        float*       codesi = codes + (size_t)r0 * 3;
        // encoder (fp32 exact-class: codes depend on z)
        enc1_gemm<<<dim3(16, mg), 256, 0, stream>>>(xi, eW1, eb1, R1);
        enc2_gemm<<<dim3( 8, mg), 256, 0, stream>>>(R1, eW2, eb2, R2);
        enc3_gemm<<<dim3( 4, mg), 256, 0, stream>>>(R2, eW3, eb3, R3);
        enc4_gemm<<<dim3( 1, mc >> 6), 256, 0, stream>>>(R3, eW4, eb4, RZ);
        // residual quantization: one fused kernel per depth
        rq_step<0><<<mc >> 6, 256, 0, stream>>>(RZ, cbt, sq, cb, RZ, ZH, RR, ZHb, codesi);
        rq_step<1><<<mc >> 6, 256, 0, stream>>>(RR, cbt, sq, cb, RZ, ZH, RR, ZHb, codesi);
        rq_step<2><<<mc >> 6, 256, 0, stream>>>(RR, cbt, sq, cb, RZ, ZH, RR, ZHb, codesi);
        // decoder in bf16 MFMA
        dec1_gemm<<<dim3(16, mg), 256, 0, stream>>>(ZHb, Wt1, db1, D1);
        dec2_gemm<<<dim3( 8, mg), 256, 0, stream>>>(D1,  Wt2, db2, D2);
        dec3_gemm<<<dim3( 4, mg), 256, 0, stream>>>(D2,  Wt3, db3, D3);
        dec4_gemm<<<dim3( 6, mg), 256, 0, stream>>>(D3,  Wt4, db4, outi);
    }
}

// Round 9
// 3923.006 us; speedup vs baseline: 1.3822x; 1.0222x over previous
//
#include <hip/hip_runtime.h>

#define FLT_MAX_C 3.402823466e+38f

typedef __attribute__((ext_vector_type(8))) __bf16 bf16x8;
typedef __attribute__((ext_vector_type(4))) float f32x4;

static __device__ __forceinline__ ushort f2bf(float x) {
    union { float f; unsigned u; } v; v.f = x;
    unsigned r = (v.u + 0x7FFFu + ((v.u >> 16) & 1u)) >> 16;
    return (ushort)r;
}

// ================= fp32 GEMM body (R3/R5-proven: BK=8, 128x128) ==========
template<bool RELU>
__device__ __forceinline__ void gemm_f32_dev(
    const float* __restrict__ A, const float* __restrict__ W,
    const float* __restrict__ bias, float* __restrict__ C, int K, int N)
{
    __shared__ float As[8][128];
    __shared__ float Bs[8][132];
    const int tid = threadIdx.x;
    const int bm = blockIdx.y << 7;
    const int bn = blockIdx.x << 7;

    const int la_row = tid >> 1;
    const int la_k   = (tid & 1) << 2;
    const int lb_row = tid >> 5;
    const int lb_col = (tid & 31) << 2;
    const int tm4 = (tid >> 4) << 2;
    const int tn4 = (tid & 15) << 2;

    float acc[8][8];
    #pragma unroll
    for (int i = 0; i < 8; ++i)
        #pragma unroll
        for (int j = 0; j < 8; ++j) acc[i][j] = 0.f;

    const float* aptr = A + (size_t)(bm + la_row) * K + la_k;
    const float* bptr = W + (size_t)lb_row * N + bn + lb_col;

    float4 av = *(const float4*)(aptr);
    float4 bv = *(const float4*)(bptr);

    for (int k0 = 0; k0 < K; k0 += 8) {
        __syncthreads();
        As[la_k + 0][la_row] = av.x;
        As[la_k + 1][la_row] = av.y;
        As[la_k + 2][la_row] = av.z;
        As[la_k + 3][la_row] = av.w;
        *(float4*)(&Bs[lb_row][lb_col]) = bv;
        __syncthreads();
        if (k0 + 8 < K) {
            av = *(const float4*)(aptr + k0 + 8);
            bv = *(const float4*)(bptr + (size_t)(k0 + 8) * N);
        }
        #pragma unroll
        for (int kk = 0; kk < 8; ++kk) {
            float a[8], b[8];
            *(float4*)(a)     = *(const float4*)(&As[kk][tm4]);
            *(float4*)(a + 4) = *(const float4*)(&As[kk][tm4 + 64]);
            *(float4*)(b)     = *(const float4*)(&Bs[kk][tn4]);
            *(float4*)(b + 4) = *(const float4*)(&Bs[kk][tn4 + 64]);
            #pragma unroll
            for (int i = 0; i < 8; ++i)
                #pragma unroll
                for (int j = 0; j < 8; ++j)
                    acc[i][j] = fmaf(a[i], b[j], acc[i][j]);
        }
    }

    float bv0[8];
    #pragma unroll
    for (int j = 0; j < 8; ++j)
        bv0[j] = bias[bn + tn4 + (j < 4 ? j : 60 + j)];

    #pragma unroll
    for (int i = 0; i < 8; ++i) {
        int row = bm + tm4 + (i < 4 ? i : 60 + i);
        float* cp = C + (size_t)row * N + bn + tn4;
        float4 v0, v1;
        v0.x = acc[i][0] + bv0[0]; v0.y = acc[i][1] + bv0[1];
        v0.z = acc[i][2] + bv0[2]; v0.w = acc[i][3] + bv0[3];
        v1.x = acc[i][4] + bv0[4]; v1.y = acc[i][5] + bv0[5];
        v1.z = acc[i][6] + bv0[6]; v1.w = acc[i][7] + bv0[7];
        if (RELU) {
            v0.x = fmaxf(v0.x, 0.f); v0.y = fmaxf(v0.y, 0.f);
            v0.z = fmaxf(v0.z, 0.f); v0.w = fmaxf(v0.w, 0.f);
            v1.x = fmaxf(v1.x, 0.f); v1.y = fmaxf(v1.y, 0.f);
            v1.z = fmaxf(v1.z, 0.f); v1.w = fmaxf(v1.w, 0.f);
        }
        *(float4*)(cp) = v0;
        *(float4*)(cp + 64) = v1;
    }
}

// ========== fp32 GEMM small-M body (BM=64, BN=128, BK=16) for enc4 ==========
template<bool RELU>
__device__ __forceinline__ void gemm_f32_64_dev(
    const float* __restrict__ A, const float* __restrict__ W,
    const float* __restrict__ bias, float* __restrict__ C, int K, int N)
{
    __shared__ float As[16][64];
    __shared__ float Bs[16][132];
    const int tid = threadIdx.x;
    const int bm = blockIdx.y << 6;
    const int bn = blockIdx.x << 7;

    const int la_row = tid & 63;
    const int la_k   = (tid >> 6) << 2;
    const int lb_row = tid >> 5;
    const int lb_col = (tid & 31) << 2;
    const int tr = tid >> 4;
    const int tc = tid & 15;

    float acc[4][8];
    #pragma unroll
    for (int i = 0; i < 4; ++i)
        #pragma unroll
        for (int j = 0; j < 8; ++j) acc[i][j] = 0.f;

    const float* aptr = A + (size_t)(bm + la_row) * K + la_k;
    const float* bptr = W + (size_t)lb_row * N + bn + lb_col;

    float4 av = *(const float4*)(aptr);
    float4 bv0 = *(const float4*)(bptr);
    float4 bv1 = *(const float4*)(bptr + (size_t)8 * N);

    for (int k0 = 0; k0 < K; k0 += 16) {
        __syncthreads();
        As[la_k + 0][la_row] = av.x;
        As[la_k + 1][la_row] = av.y;
        As[la_k + 2][la_row] = av.z;
        As[la_k + 3][la_row] = av.w;
        *(float4*)(&Bs[lb_row][lb_col]) = bv0;
        *(float4*)(&Bs[lb_row + 8][lb_col]) = bv1;
        __syncthreads();
        if (k0 + 16 < K) {
            av  = *(const float4*)(aptr + k0 + 16);
            bv0 = *(const float4*)(bptr + (size_t)(k0 + 16) * N);
            bv1 = *(const float4*)(bptr + (size_t)(k0 + 24) * N);
        }
        #pragma unroll
        for (int kk = 0; kk < 16; ++kk) {
            float a[4], b[8];
            *(float4*)(a) = *(const float4*)(&As[kk][tr << 2]);
            *(float4*)(b)     = *(const float4*)(&Bs[kk][tc << 2]);
            *(float4*)(b + 4) = *(const float4*)(&Bs[kk][(tc << 2) + 64]);
            #pragma unroll
            for (int i = 0; i < 4; ++i)
                #pragma unroll
                for (int j = 0; j < 8; ++j)
                    acc[i][j] = fmaf(a[i], b[j], acc[i][j]);
        }
    }

    float bb[8];
    #pragma unroll
    for (int j = 0; j < 8; ++j)
        bb[j] = bias[bn + (tc << 2) + (j < 4 ? j : 60 + j)];

    #pragma unroll
    for (int i = 0; i < 4; ++i) {
        float* cp = C + (size_t)(bm + (tr << 2) + i) * N + bn + (tc << 2);
        float4 v0, v1;
        v0.x = acc[i][0] + bb[0]; v0.y = acc[i][1] + bb[1];
        v0.z = acc[i][2] + bb[2]; v0.w = acc[i][3] + bb[3];
        v1.x = acc[i][4] + bb[4]; v1.y = acc[i][5] + bb[5];
        v1.z = acc[i][6] + bb[6]; v1.w = acc[i][7] + bb[7];
        if (RELU) {
            v0.x = fmaxf(v0.x, 0.f); v0.y = fmaxf(v0.y, 0.f);
            v0.z = fmaxf(v0.z, 0.f); v0.w = fmaxf(v0.w, 0.f);
            v1.x = fmaxf(v1.x, 0.f); v1.y = fmaxf(v1.y, 0.f);
            v1.z = fmaxf(v1.z, 0.f); v1.w = fmaxf(v1.w, 0.f);
        }
        *(float4*)(cp) = v0;
        *(float4*)(cp + 64) = v1;
    }
}

// ================= bf16 MFMA GEMM device body (decoder) =================
template<bool RELU, bool OUTF32>
__device__ __forceinline__ void gemm_bf16_dev(
    const ushort* __restrict__ A, const ushort* __restrict__ Wt,
    const float* __restrict__ bias, void* __restrict__ C, int K, int N)
{
    __shared__ __align__(16) ushort As[128][64];
    __shared__ __align__(16) ushort Bs[128][64];
    const int tid  = threadIdx.x;
    const int lane = tid & 63;
    const int wv   = tid >> 6;
    const int wm   = (wv >> 1) << 6;
    const int wn   = (wv & 1) << 6;
    const int bm   = blockIdx.y << 7;
    const int bn   = blockIdx.x << 7;
    const int lr   = lane & 15;
    const int lh   = lane >> 4;

    f32x4 acc[4][4];
    #pragma unroll
    for (int m = 0; m < 4; ++m)
        #pragma unroll
        for (int n = 0; n < 4; ++n) acc[m][n] = (f32x4){0.f, 0.f, 0.f, 0.f};

    for (int k0 = 0; k0 < K; k0 += 64) {
        __syncthreads();
        #pragma unroll
        for (int i = 0; i < 4; ++i) {
            const int c    = wv * 4 + i;
            const int boff = c * 1024 + lane * 16;
            const int r    = boff >> 7;
            const int cbt  = boff & 127;
            const char* sa = (const char*)A  + (((size_t)(bm + r) * K + k0) << 1) + cbt;
            const char* sb = (const char*)Wt + (((size_t)(bn + r) * K + k0) << 1) + cbt;
            __builtin_amdgcn_global_load_lds((const void*)sa, (void*)(&As[0][0] + c * 512), 16, 0, 0);
            __builtin_amdgcn_global_load_lds((const void*)sb, (void*)(&Bs[0][0] + c * 512), 16, 0, 0);
        }
        __syncthreads();
        #pragma unroll
        for (int kk = 0; kk < 64; kk += 32) {
            bf16x8 af[4], bfr[4];
            #pragma unroll
            for (int m = 0; m < 4; ++m)
                af[m] = *(const bf16x8*)&As[wm + m * 16 + lr][kk + lh * 8];
            #pragma unroll
            for (int n = 0; n < 4; ++n)
                bfr[n] = *(const bf16x8*)&Bs[wn + n * 16 + lr][kk + lh * 8];
            #pragma unroll
            for (int m = 0; m < 4; ++m)
                #pragma unroll
                for (int n = 0; n < 4; ++n)
                    acc[m][n] = __builtin_amdgcn_mfma_f32_16x16x32_bf16(
                        af[m], bfr[n], acc[m][n], 0, 0, 0);
        }
    }

    #pragma unroll
    for (int n = 0; n < 4; ++n) {
        const int col = bn + wn + n * 16 + lr;
        const float bcol = bias[col];
        #pragma unroll
        for (int m = 0; m < 4; ++m) {
            #pragma unroll
            for (int i = 0; i < 4; ++i) {
                const int row = bm + wm + m * 16 + lh * 4 + i;
                float v = acc[m][n][i] + bcol;
                if (RELU) v = fmaxf(v, 0.f);
                if (OUTF32) ((float*)C)[(size_t)row * N + col] = v;
                else        ((ushort*)C)[(size_t)row * N + col] = f2bf(v);
            }
        }
    }
}

// ---- named wrappers ----
__global__ __launch_bounds__(256) void enc1_gemm(const float* A, const float* W, const float* b, float* C)
{ gemm_f32_dev<true>(A, W, b, C, 768, 2048); }
__global__ __launch_bounds__(256) void enc2_gemm(const float* A, const float* W, const float* b, float* C)
{ gemm_f32_dev<true>(A, W, b, C, 2048, 1024); }
__global__ __launch_bounds__(256) void enc3_gemm(const float* A, const float* W, const float* b, float* C)
{ gemm_f32_dev<true>(A, W, b, C, 1024, 512); }
__global__ __launch_bounds__(256) void enc4_gemm(const float* A, const float* W, const float* b, float* C)
{ gemm_f32_64_dev<false>(A, W, b, C, 512, 128); }
__global__ __launch_bounds__(256) void dec1_gemm(const ushort* A, const ushort* Wt, const float* b, void* C)
{ gemm_bf16_dev<true, false>(A, Wt, b, C, 128, 2048); }
__global__ __launch_bounds__(256) void dec2_gemm(const ushort* A, const ushort* Wt, const float* b, void* C)
{ gemm_bf16_dev<true, false>(A, Wt, b, C, 2048, 1024); }
__global__ __launch_bounds__(256) void dec3_gemm(const ushort* A, const ushort* Wt, const float* b, void* C)
{ gemm_bf16_dev<true, false>(A, Wt, b, C, 1024, 512); }
__global__ __launch_bounds__(256) void dec4_gemm(const ushort* A, const ushort* Wt, const float* b, void* C)
{ gemm_bf16_dev<false, true>(A, Wt, b, C, 512, 768); }

// ---------------- weight convert+transpose: W[K][N] f32 -> Wt[N][K] bf16 ----
__global__ __launch_bounds__(256) void wt_convert(
    const float* __restrict__ W, ushort* __restrict__ Wt, int K, int N)
{
    __shared__ ushort t[64][65];
    const int kb = blockIdx.y << 6, nb = blockIdx.x << 6;
    const int c  = threadIdx.x & 63;
    const int r0 = (threadIdx.x >> 6) << 4;
    #pragma unroll
    for (int i = 0; i < 16; ++i)
        t[r0 + i][c] = f2bf(W[(size_t)(kb + r0 + i) * N + nb + c]);
    __syncthreads();
    #pragma unroll
    for (int i = 0; i < 16; ++i)
        Wt[(size_t)(nb + r0 + i) * K + kb + c] = t[c][r0 + i];
}

// ---------------- codebook prep ----------------
__global__ __launch_bounds__(256) void cbsq_kernel(
    const float* __restrict__ cb, float* __restrict__ cbsq)
{
    int k = blockIdx.x * 256 + threadIdx.x;
    const float* r = cb + ((size_t)k << 7);
    float s = 0.f;
    #pragma unroll 8
    for (int d = 0; d < 128; ++d) s = fmaf(r[d], r[d], s);
    cbsq[k] = s;
}

// cbt[d][k] = cb[k][d] : [128][1024] f32.  grid (16, 2)
__global__ __launch_bounds__(256) void cbt_kernel(
    const float* __restrict__ cb, float* __restrict__ cbt)
{
    __shared__ float t[64][65];
    const int kb = blockIdx.x << 6;
    const int db = blockIdx.y << 6;
    const int c  = threadIdx.x & 63;
    const int r0 = (threadIdx.x >> 6) << 4;
    #pragma unroll
    for (int i = 0; i < 16; ++i)
        t[r0 + i][c] = cb[(size_t)(kb + r0 + i) * 128 + db + c];
    __syncthreads();
    #pragma unroll
    for (int i = 0; i < 16; ++i)
        cbt[(size_t)(db + r0 + i) * 1024 + kb + c] = t[c][r0 + i];
}

// ---------------- fully-fused residual quantization (all 3 depths) --------
// Block owns 64 rows for the whole RQ. Residue lives in LDS transposed
// (As[d][row], padded), z_hat in registers, cbsq in LDS. Per depth:
// GEMM over 8 col-tiles of cbt (BK=32, proven 2-barrier staging) -> running
// first-min -> 16-lane tie-break reduce -> block-local update with the exact
// reference rounding chain (zh += cb[best]; residue = z - zh).
__global__ __launch_bounds__(256) void rq_all(
    const float* __restrict__ z, const float* __restrict__ cbt,
    const float* __restrict__ sq, const float* __restrict__ cb,
    ushort* __restrict__ ZHb, float* __restrict__ codes)
{
    __shared__ float As[128][68];     // residue^T, padded (16B-aligned rows)
    __shared__ float Bs[32][132];
    __shared__ float sqs[1024];
    __shared__ float rrs[64];

    const int tid = threadIdx.x;
    const int bm  = blockIdx.x << 6;
    const int tr  = tid >> 4;          // row group: rows tr*4..+3
    const int c   = tid & 15;          // d-slice: d = c*8..c*8+7
    const int tn4 = c << 2;
    const int lb_row = tid >> 5;
    const int lb_col = (tid & 31) << 2;

    #pragma unroll
    for (int i = 0; i < 4; ++i) sqs[tid + (i << 8)] = sq[tid + (i << 8)];

    // ---- init: z -> As (transposed), zh = 0, rr per row ----
    float zh[4][8];
    #pragma unroll
    for (int i = 0; i < 4; ++i) {
        const int r_  = (tr << 2) + i;
        const float* zp = z + (size_t)(bm + r_) * 128 + (c << 3);
        float4 z0 = *(const float4*)(zp);
        float4 z1 = *(const float4*)(zp + 4);
        #pragma unroll
        for (int j = 0; j < 8; ++j) zh[i][j] = 0.f;
        As[(c << 3) + 0][r_] = z0.x; As[(c << 3) + 1][r_] = z0.y;
        As[(c << 3) + 2][r_] = z0.z; As[(c << 3) + 3][r_] = z0.w;
        As[(c << 3) + 4][r_] = z1.x; As[(c << 3) + 5][r_] = z1.y;
        As[(c << 3) + 6][r_] = z1.z; As[(c << 3) + 7][r_] = z1.w;
        float p = z0.x * z0.x;
        p = fmaf(z0.y, z0.y, p); p = fmaf(z0.z, z0.z, p);
        p = fmaf(z0.w, z0.w, p); p = fmaf(z1.x, z1.x, p);
        p = fmaf(z1.y, z1.y, p); p = fmaf(z1.z, z1.z, p);
        p = fmaf(z1.w, z1.w, p);
        #pragma unroll
        for (int o = 8; o >= 1; o >>= 1) p += __shfl_xor(p, o);
        if (c == 0) rrs[r_] = p;
    }
    __syncthreads();

    for (int t = 0; t < 3; ++t) {
        float rr_[4];
        #pragma unroll
        for (int i = 0; i < 4; ++i) rr_[i] = rrs[(tr << 2) + i];

        float best_d[4] = {FLT_MAX_C, FLT_MAX_C, FLT_MAX_C, FLT_MAX_C};
        int   best_i[4] = {0, 0, 0, 0};

        for (int bx = 0; bx < 8; ++bx) {
            const int bn = bx << 7;
            const float* bptr = cbt + (size_t)lb_row * 1024 + bn + lb_col;
            float4 bv0 = *(const float4*)(bptr);
            float4 bv1 = *(const float4*)(bptr + (size_t)8  * 1024);
            float4 bv2 = *(const float4*)(bptr + (size_t)16 * 1024);
            float4 bv3 = *(const float4*)(bptr + (size_t)24 * 1024);

            float acc[4][8];
            #pragma unroll
            for (int i = 0; i < 4; ++i)
                #pragma unroll
                for (int j = 0; j < 8; ++j) acc[i][j] = 0.f;

            for (int k0 = 0; k0 < 128; k0 += 32) {
                __syncthreads();
                *(float4*)(&Bs[lb_row +  0][lb_col]) = bv0;
                *(float4*)(&Bs[lb_row +  8][lb_col]) = bv1;
                *(float4*)(&Bs[lb_row + 16][lb_col]) = bv2;
                *(float4*)(&Bs[lb_row + 24][lb_col]) = bv3;
                __syncthreads();
                if (k0 + 32 < 128) {
                    bv0 = *(const float4*)(bptr + (size_t)(k0 + 32) * 1024);
                    bv1 = *(const float4*)(bptr + (size_t)(k0 + 40) * 1024);
                    bv2 = *(const float4*)(bptr + (size_t)(k0 + 48) * 1024);
                    bv3 = *(const float4*)(bptr + (size_t)(k0 + 56) * 1024);
                }
                #pragma unroll
                for (int kk = 0; kk < 32; ++kk) {
                    float a[4], b[8];
                    *(float4*)(a)     = *(const float4*)(&As[k0 + kk][tr << 2]);
                    *(float4*)(b)     = *(const float4*)(&Bs[kk][tn4]);
                    *(float4*)(b + 4) = *(const float4*)(&Bs[kk][tn4 + 64]);
                    #pragma unroll
                    for (int i = 0; i < 4; ++i)
                        #pragma unroll
                        for (int j = 0; j < 8; ++j)
                            acc[i][j] = fmaf(a[i], b[j], acc[i][j]);
                }
            }
            // running first-min (cols ascending: bx outer, j inner)
            #pragma unroll
            for (int i = 0; i < 4; ++i) {
                #pragma unroll
                for (int j = 0; j < 8; ++j) {
                    const int col = bn + tn4 + (j < 4 ? j : 60 + j);
                    float d = (rr_[i] + sqs[col]) - 2.f * acc[i][j];
                    if (d < best_d[i]) { best_d[i] = d; best_i[i] = col; }
                }
            }
        }

        // 16-lane group reduce (first-min tie-break)
        #pragma unroll
        for (int i = 0; i < 4; ++i) {
            float bd = best_d[i]; int bi = best_i[i];
            #pragma unroll
            for (int o = 8; o >= 1; o >>= 1) {
                float od = __shfl_xor(bd, o);
                int   oi = __shfl_xor(bi, o);
                if (od < bd || (od == bd && oi < bi)) { bd = od; bi = oi; }
            }
            best_i[i] = bi;
        }

        __syncthreads();   // all As reads of this depth complete

        #pragma unroll
        for (int i = 0; i < 4; ++i) {
            const int r_  = (tr << 2) + i;
            const int row = bm + r_;
            if (c == 0) codes[(size_t)row * 3 + t] = (float)best_i[i];

            const float* cbp = cb + ((size_t)best_i[i] << 7) + (c << 3);
            float4 c0 = *(const float4*)(cbp);
            float4 c1 = *(const float4*)(cbp + 4);
            zh[i][0] += c0.x; zh[i][1] += c0.y;
            zh[i][2] += c0.z; zh[i][3] += c0.w;
            zh[i][4] += c1.x; zh[i][5] += c1.y;
            zh[i][6] += c1.z; zh[i][7] += c1.w;

            if (t < 2) {
                const float* zp = z + (size_t)row * 128 + (c << 3);
                float4 z0 = *(const float4*)(zp);
                float4 z1 = *(const float4*)(zp + 4);
                float r0 = z0.x - zh[i][0], r1 = z0.y - zh[i][1];
                float r2 = z0.z - zh[i][2], r3 = z0.w - zh[i][3];
                float r4 = z1.x - zh[i][4], r5 = z1.y - zh[i][5];
                float r6 = z1.z - zh[i][6], r7 = z1.w - zh[i][7];
                As[(c << 3) + 0][r_] = r0; As[(c << 3) + 1][r_] = r1;
                As[(c << 3) + 2][r_] = r2; As[(c << 3) + 3][r_] = r3;
                As[(c << 3) + 4][r_] = r4; As[(c << 3) + 5][r_] = r5;
                As[(c << 3) + 6][r_] = r6; As[(c << 3) + 7][r_] = r7;
                float p = r0 * r0;
                p = fmaf(r1, r1, p); p = fmaf(r2, r2, p);
                p = fmaf(r3, r3, p); p = fmaf(r4, r4, p);
                p = fmaf(r5, r5, p); p = fmaf(r6, r6, p);
                p = fmaf(r7, r7, p);
                #pragma unroll
                for (int o = 8; o >= 1; o >>= 1) p += __shfl_xor(p, o);
                if (c == 0) rrs[r_] = p;
            } else {
                ushort4 o0, o1;
                o0.x = f2bf(zh[i][0]); o0.y = f2bf(zh[i][1]);
                o0.z = f2bf(zh[i][2]); o0.w = f2bf(zh[i][3]);
                o1.x = f2bf(zh[i][4]); o1.y = f2bf(zh[i][5]);
                o1.z = f2bf(zh[i][6]); o1.w = f2bf(zh[i][7]);
                ushort* zbp = ZHb + (size_t)row * 128 + (c << 3);
                *(ushort4*)(zbp)     = o0;
                *(ushort4*)(zbp + 4) = o1;
            }
        }
        if (t < 2) __syncthreads();   // As/rrs visible before next depth
    }
}

extern "C" void kernel_launch(void* const* d_in, const int* in_sizes, int n_in,
                              void* d_out, int out_size, void* d_ws, size_t ws_size,
                              hipStream_t stream)
{
    const float* x   = (const float*)d_in[0];
    const float* eW1 = (const float*)d_in[1];
    const float* eb1 = (const float*)d_in[2];
    const float* eW2 = (const float*)d_in[3];
    const float* eb2 = (const float*)d_in[4];
    const float* eW3 = (const float*)d_in[5];
    const float* eb3 = (const float*)d_in[6];
    const float* eW4 = (const float*)d_in[7];
    const float* eb4 = (const float*)d_in[8];
    const float* dW1 = (const float*)d_in[9];
    const float* db1 = (const float*)d_in[10];
    const float* dW2 = (const float*)d_in[11];
    const float* db2 = (const float*)d_in[12];
    const float* dW3 = (const float*)d_in[13];
    const float* db3 = (const float*)d_in[14];
    const float* dW4 = (const float*)d_in[15];
    const float* db4 = (const float*)d_in[16];
    const float* cb  = (const float*)d_in[17];

    float* out   = (float*)d_out;
    float* codes = out + (size_t)32768 * 768;

    // ---- fixed region: dec Wt bf16 | cbsq | CBt f32 ----
    ushort* Wt1 = (ushort*)d_ws;                       // 2048 x 128
    ushort* Wt2 = Wt1 + (size_t)2048 * 128;            // 1024 x 2048
    ushort* Wt3 = Wt2 + (size_t)1024 * 2048;           // 512 x 1024
    ushort* Wt4 = Wt3 + (size_t)512 * 1024;            // 768 x 512
    float*  sq  = (float*)(Wt4 + (size_t)768 * 512);   // 1024
    float*  cbt = sq + 1024;                           // 128 x 1024
    float*  act = cbt + (size_t)128 * 1024;
    const size_t fixed_b = (char*)act - (char*)d_ws;

    int mc = 32768;
    while (mc > 1024) {
        if (fixed_b + (size_t)mc * 15104 <= ws_size) break;
        mc >>= 1;
    }

    float*  R1  = act;                               // mc x 2048 f32
    float*  R2  = R1 + (size_t)mc * 2048;            // mc x 1024 f32
    float*  R3  = R2 + (size_t)mc * 1024;            // mc x 512  f32
    float*  RZ  = R3 + (size_t)mc * 512;             // mc x 128  f32 (z)
    ushort* ZHb = (ushort*)(RZ + (size_t)mc * 128);  // mc x 128 bf16
    ushort* D1  = (ushort*)R1;
    ushort* D2  = (ushort*)R2;
    ushort* D3  = (ushort*)R3;

    wt_convert<<<dim3(2048 / 64, 128 / 64), 256, 0, stream>>>(dW1, Wt1, 128, 2048);
    wt_convert<<<dim3(1024 / 64, 2048 / 64), 256, 0, stream>>>(dW2, Wt2, 2048, 1024);
    wt_convert<<<dim3(512 / 64, 1024 / 64), 256, 0, stream>>>(dW3, Wt3, 1024, 512);
    wt_convert<<<dim3(768 / 64, 512 / 64), 256, 0, stream>>>(dW4, Wt4, 512, 768);
    cbsq_kernel<<<4, 256, 0, stream>>>(cb, sq);
    cbt_kernel<<<dim3(16, 2), 256, 0, stream>>>(cb, cbt);

    const int mg = mc >> 7;
    for (int r0 = 0; r0 < 32768; r0 += mc) {
        const float* xi     = x     + (size_t)r0 * 768;
        float*       outi   = out   + (size_t)r0 * 768;
        float*       codesi = codes + (size_t)r0 * 3;
        // encoder (fp32 exact-class: codes depend on z)
        enc1_gemm<<<dim3(16, mg), 256, 0, stream>>>(xi, eW1, eb1, R1);
        enc2_gemm<<<dim3( 8, mg), 256, 0, stream>>>(R1, eW2, eb2, R2);
        enc3_gemm<<<dim3( 4, mg), 256, 0, stream>>>(R2, eW3, eb3, R3);
        enc4_gemm<<<dim3( 1, mc >> 6), 256, 0, stream>>>(R3, eW4, eb4, RZ);
        // residual quantization: single fused kernel, all 3 depths
        rq_all<<<mc >> 6, 256, 0, stream>>>(RZ, cbt, sq, cb, ZHb, codesi);
        // decoder in bf16 MFMA
        dec1_gemm<<<dim3(16, mg), 256, 0, stream>>>(ZHb, Wt1, db1, D1);
        dec2_gemm<<<dim3( 8, mg), 256, 0, stream>>>(D1,  Wt2, db2, D2);
        dec3_gemm<<<dim3( 4, mg), 256, 0, stream>>>(D2,  Wt3, db3, D3);
        dec4_gemm<<<dim3( 6, mg), 256, 0, stream>>>(D3,  Wt4, db4, outi);
    }
}